// Round 5
// baseline (170.112 us; speedup 1.0000x reference)
//
#include <hip/hip_runtime.h>

#define BB   4
#define QS   512
#define KSZ  1024
#define DD   512
#define HH   128
#define DVV  512

typedef unsigned int uint;
typedef unsigned short ushort;
typedef __attribute__((ext_vector_type(8)))  short short8;   // 8 bf16 (4 VGPRs)
typedef __attribute__((ext_vector_type(16))) float f32x16;   // MFMA 32x32 acc

__device__ __forceinline__ float rcp_fast(float x)  { return __builtin_amdgcn_rcpf(x); }
__device__ __forceinline__ float exp2_fast(float x) { return __builtin_amdgcn_exp2f(x); }

// split fp32 -> bf16 hi (truncate) + bf16 lo (residual); ~2^-17 rel combined
__device__ __forceinline__ void split1(float v, ushort& h, ushort& l) {
    uint u = __float_as_uint(v);
    h = (ushort)(u >> 16);
    float r = v - __uint_as_float(u & 0xffff0000u);
    l = (ushort)(__float_as_uint(r) >> 16);
}

#define NVT (BB * (KSZ / 32) * (DVV / 32))   // 2048 vt blocks
#define NQ8 (BB * QS / 8)                    // 256 proj-q blocks
#define NK8 (BB * KSZ / 8)                   // 512 proj-k blocks

// ---------------------------------------------------------------------------
// Kernel 1 (fused): blocks [0,NVT) transpose+split V; the rest do the
// projection GEMM + exp(2x), 8 rows/block (768 blocks -> ~3/CU, no tail).
// vt is memory-bound, proj compute-bound -> they overlap in one launch.
// ---------------------------------------------------------------------------
__global__ __launch_bounds__(256) void prep_kernel(
    const float* __restrict__ q,  const float* __restrict__ k,
    const float* __restrict__ val,
    const float* __restrict__ Wq, const float* __restrict__ Wk,
    float* __restrict__ eq, float* __restrict__ ek,
    ushort* __restrict__ vhi, ushort* __restrict__ vlo)
{
    const int id  = blockIdx.x;
    const int tid = threadIdx.x;

    if (id < NVT) {
        // ---- V transpose + bf16 split: [b][k][n] fp32 -> [b][n][k] hi/lo ----
        __shared__ float Ts[32][33];
        const int b   = id >> 9;            // 512 blocks per batch
        const int rem = id & 511;
        const int k0  = (rem >> 4) * 32;    // 32 k-tiles
        const int n0  = (rem & 15) * 32;    // 16 n-tiles
        {
            const int kk = tid >> 3, n4 = (tid & 7) * 4;
            float4 v = *(const float4*)&val[((size_t)b * KSZ + k0 + kk) * DVV + n0 + n4];
            Ts[kk][n4 + 0] = v.x; Ts[kk][n4 + 1] = v.y;
            Ts[kk][n4 + 2] = v.z; Ts[kk][n4 + 3] = v.w;
        }
        __syncthreads();
        {
            const int nn = tid >> 3, k4 = (tid & 7) * 4;
            ushort h[4], l[4];
            #pragma unroll
            for (int i = 0; i < 4; i++) split1(Ts[k4 + i][nn], h[i], l[i]);
            size_t o = ((size_t)b * DVV + n0 + nn) * KSZ + k0 + k4;
            *(ushort4*)&vhi[o] = make_ushort4(h[0], h[1], h[2], h[3]);
            *(ushort4*)&vlo[o] = make_ushort4(l[0], l[1], l[2], l[3]);
        }
        return;
    }

    // ---- projection + exp(2x): out[m][h] = exp2(C2L * dot(A[m,:],W[:,h])) ----
    __shared__ float At[8][36];
    __shared__ float Wt[32][128];

    const int pid = id - NVT;
    const float* A; const float* W; float* outp; int m0;
    if (pid < NQ8) { A = q; W = Wq; outp = eq; m0 = pid * 8; }
    else           { A = k; W = Wk; outp = ek; m0 = (pid - NQ8) * 8; }

    const int h4 = tid & 31;
    const int r  = tid >> 5;           // one row each (8 rows)

    float4 acc = {0.f, 0.f, 0.f, 0.f};

    for (int d0 = 0; d0 < DD; d0 += 32) {
        if (tid < 64) {                    // 8x32 A tile = 64 float4
            int row = tid >> 3, c4 = tid & 7;
            *(float4*)&At[row][c4 * 4] =
                *(const float4*)&A[(size_t)(m0 + row) * DD + d0 + c4 * 4];
        }
        #pragma unroll
        for (int i = 0; i < 4; i++) {      // 32x128 W tile = 1024 float4
            int f = tid + i * 256;
            int row = f >> 5, c4 = f & 31;
            *(float4*)&Wt[row][c4 * 4] =
                *(const float4*)&W[(size_t)(d0 + row) * HH + c4 * 4];
        }
        __syncthreads();
        #pragma unroll 8
        for (int kk = 0; kk < 32; kk++) {
            float4 w4 = *(const float4*)&Wt[kk][h4 * 4];
            float a0 = At[r][kk];
            acc.x = fmaf(a0, w4.x, acc.x); acc.y = fmaf(a0, w4.y, acc.y);
            acc.z = fmaf(a0, w4.z, acc.z); acc.w = fmaf(a0, w4.w, acc.w);
        }
        __syncthreads();
    }

    const float C2L = 2.8853900817779268f;  // 2*log2(e)
    float4 o;
    o.x = exp2_fast(acc.x * C2L); o.y = exp2_fast(acc.y * C2L);
    o.z = exp2_fast(acc.z * C2L); o.w = exp2_fast(acc.w * C2L);
    *(float4*)&outp[(size_t)(m0 + r) * HH + h4 * 4] = o;
}

// ---------------------------------------------------------------------------
// Kernel 2: P = exp(-2 * sum_h w_v[h]*rcp(eq*ek+1)) emitted as bf16 hi/lo
// (Phi/Plo) + per-64k-tile row-sum partials rsp[b][q][16]. wv read via
// uniform (scalar) loads. Constant sum(w_v) dropped (cancels in softmax).
// ---------------------------------------------------------------------------
__global__ __launch_bounds__(256) void scores_kernel(
    const float* __restrict__ eq, const float* __restrict__ ek,
    const float* __restrict__ wv, ushort* __restrict__ Phi,
    ushort* __restrict__ Plo, float* __restrict__ rsp)
{
    __shared__ float eqs[64][68];
    __shared__ float eks[64][68];

    const int tid = threadIdx.x;
    const int b  = blockIdx.z;
    const int q0 = blockIdx.y * 64;
    const int k0 = blockIdx.x * 64;

    const float* eqb = eq + ((size_t)b * QS  + q0) * HH;
    const float* ekb = ek + ((size_t)b * KSZ + k0) * HH;

    const int tk = tid & 15;
    const int tq = tid >> 4;

    float acc[4][4] = {};

    for (int hc = 0; hc < HH; hc += 64) {
        __syncthreads();
        #pragma unroll
        for (int i = 0; i < 4; i++) {
            int f = tid + i * 256;
            int row = f >> 4, c4 = f & 15;
            *(float4*)&eqs[row][c4 * 4] =
                *(const float4*)&eqb[(size_t)row * HH + hc + c4 * 4];
            *(float4*)&eks[row][c4 * 4] =
                *(const float4*)&ekb[(size_t)row * HH + hc + c4 * 4];
        }
        __syncthreads();

        for (int h0 = 0; h0 < 64; h0 += 4) {
            float4 wv4 = *(const float4*)&wv[hc + h0];   // uniform -> s_load
            float4 eq4[4], ek4[4];
            #pragma unroll
            for (int j = 0; j < 4; j++) {
                eq4[j] = *(const float4*)&eqs[tq + 16 * j][h0];
                ek4[j] = *(const float4*)&eks[tk + 16 * j][h0];
            }
            #pragma unroll
            for (int jq = 0; jq < 4; jq++) {
                #pragma unroll
                for (int jk = 0; jk < 4; jk++) {
                    acc[jq][jk] = fmaf(wv4.x, rcp_fast(fmaf(eq4[jq].x, ek4[jk].x, 1.0f)), acc[jq][jk]);
                    acc[jq][jk] = fmaf(wv4.y, rcp_fast(fmaf(eq4[jq].y, ek4[jk].y, 1.0f)), acc[jq][jk]);
                    acc[jq][jk] = fmaf(wv4.z, rcp_fast(fmaf(eq4[jq].z, ek4[jk].z, 1.0f)), acc[jq][jk]);
                    acc[jq][jk] = fmaf(wv4.w, rcp_fast(fmaf(eq4[jq].w, ek4[jk].w, 1.0f)), acc[jq][jk]);
                }
            }
        }
    }

    const float CN = -2.8853900817779268f;  // -2*log2(e)
    ushort* ph = Phi + ((size_t)b * QS + q0) * KSZ + k0;
    ushort* pl = Plo + ((size_t)b * QS + q0) * KSZ + k0;
    #pragma unroll
    for (int jq = 0; jq < 4; jq++) {
        float rowp = 0.f;
        #pragma unroll
        for (int jk = 0; jk < 4; jk++) {
            float pv_ = exp2_fast(acc[jq][jk] * CN);
            ushort hh, ll; split1(pv_, hh, ll);
            size_t o = (size_t)(tq + 16 * jq) * KSZ + tk + 16 * jk;
            ph[o] = hh; pl[o] = ll;
            rowp += pv_;
        }
        #pragma unroll
        for (int m = 8; m; m >>= 1) rowp += __shfl_xor(rowp, m);
        if ((tid & 15) == 0)
            rsp[((size_t)b * QS + q0 + tq + 16 * jq) * 16 + blockIdx.x] = rowp;
    }
}

// ---------------------------------------------------------------------------
// Kernel 3: out = P @ V / rowsum via MFMA, all-bf16 operands (3 products:
// PhVh + PhVl + PlVh; PlVl ~2^-34, dropped). No LDS staging: frags straight
// from Phi/Plo/vhi/vlo (k-contiguous 16B loads). 512 blocks x 4 waves:
// waves = 2 m-subtiles x 2 K-halves (partials merged via LDS) -> 2 blocks/CU,
// 2 waves/SIMD. XCD swizzle (id&7): one batch per XCD-pair -> V slab 2 MB +
// P slab 1 MB resident in 4 MB L2.
// ---------------------------------------------------------------------------
__global__ __launch_bounds__(256) void pv_mfma_kernel(
    const ushort* __restrict__ Phi, const ushort* __restrict__ Plo,
    const ushort* __restrict__ vhi, const ushort* __restrict__ vlo,
    const float* __restrict__ rsp, float* __restrict__ outp)
{
    __shared__ float invs[64];
    __shared__ float accs[2][32][33];

    const int id = blockIdx.x;          // 512 blocks
    const int x  = id & 7;              // ~XCD
    const int j  = id >> 3;             // 0..63
    const int b  = x >> 1;
    const int mt = (x & 1) * 4 + (j >> 4);   // 0..7  (m-tile of 64)
    const int nt = j & 15;                   // 0..15 (n-tile of 32)

    const int tid = threadIdx.x, w = tid >> 6, lane = tid & 63;

    if (tid < 64) {
        const float* rp = rsp + ((size_t)b * QS + mt * 64 + tid) * 16;
        float s = 0.f;
        #pragma unroll
        for (int i = 0; i < 16; i++) s += rp[i];
        invs[tid] = rcp_fast(s);
    }

    const int mw  = mt * 64 + (w & 1) * 32;
    const int kh  = (w >> 1) * (KSZ / 2);
    const int row = lane & 31, kg = lane >> 5;
    const int nb  = nt * 32;

    const ushort* pah = Phi + ((size_t)b * QS  + mw + row) * KSZ + kh;
    const ushort* pal = Plo + ((size_t)b * QS  + mw + row) * KSZ + kh;
    const ushort* bhp = vhi + ((size_t)b * DVV + nb + row) * KSZ + kh;
    const ushort* blp = vlo + ((size_t)b * DVV + nb + row) * KSZ + kh;

    f32x16 acc;
    #pragma unroll
    for (int i = 0; i < 16; i++) acc[i] = 0.f;

    #pragma unroll 8
    for (int kb = 0; kb < KSZ / 2; kb += 16) {
        const int ka = kb + kg * 8;
        short8 ah = *(const short8*)(pah + ka);
        short8 al = *(const short8*)(pal + ka);
        short8 vh = *(const short8*)(bhp + ka);
        short8 vl = *(const short8*)(blp + ka);
        acc = __builtin_amdgcn_mfma_f32_32x32x16_bf16(ah, vh, acc, 0, 0, 0);
        acc = __builtin_amdgcn_mfma_f32_32x32x16_bf16(ah, vl, acc, 0, 0, 0);
        acc = __builtin_amdgcn_mfma_f32_32x32x16_bf16(al, vh, acc, 0, 0, 0);
    }

    // C/D layout (m74/m101): col = lane&31, row = (r&3) + 8*(r>>2) + 4*kg
    if (w >= 2) {
        #pragma unroll
        for (int r = 0; r < 16; r++)
            accs[w - 2][(r & 3) + 8 * (r >> 2) + 4 * kg][row] = acc[r];
    }
    __syncthreads();
    if (w < 2) {
        float* ob = outp + ((size_t)b * QS + mw) * DVV + nb;
        #pragma unroll
        for (int r = 0; r < 16; r++) {
            const int rb = (r & 3) + 8 * (r >> 2) + 4 * kg;
            float v = acc[r] + accs[w][rb][row];
            ob[(size_t)rb * DVV + row] = v * invs[(w & 1) * 32 + rb];
        }
    }
}

// ---------------------------------------------------------------------------
extern "C" void kernel_launch(void* const* d_in, const int* in_sizes, int n_in,
                              void* d_out, int out_size, void* d_ws, size_t ws_size,
                              hipStream_t stream)
{
    const float* queries = (const float*)d_in[0];
    const float* keys    = (const float*)d_in[1];
    const float* values  = (const float*)d_in[2];
    const float* Wq      = (const float*)d_in[3];
    const float* Wk      = (const float*)d_in[4];
    const float* wv      = (const float*)d_in[5];
    float* out = (float*)d_out;

    // ws: eq 1MB | ek 2MB | rsp 128KB | Phi 4MB | Plo 4MB | vhi 4MB | vlo 4MB
    float*  eq  = (float*)d_ws;
    float*  ek  = eq + (size_t)BB * QS * HH;
    float*  rsp = ek + (size_t)BB * KSZ * HH;
    ushort* Phi = (ushort*)(rsp + (size_t)BB * QS * 16);
    ushort* Plo = Phi + (size_t)BB * QS * KSZ;
    ushort* vhi = Plo + (size_t)BB * QS * KSZ;
    ushort* vlo = vhi + (size_t)BB * KSZ * DVV;

    prep_kernel<<<dim3(NVT + NQ8 + NK8), 256, 0, stream>>>(
        queries, keys, values, Wq, Wk, eq, ek, vhi, vlo);

    scores_kernel<<<dim3(KSZ / 64, QS / 64, BB), 256, 0, stream>>>(
        eq, ek, wv, Phi, Plo, rsp);

    pv_mfma_kernel<<<dim3(512), 256, 0, stream>>>(Phi, Plo, vhi, vlo, rsp, out);
}